// Round 8
// baseline (431.591 us; speedup 1.0000x reference)
//
#include <hip/hip_runtime.h>
#include <hip/hip_cooperative_groups.h>

namespace cg = cooperative_groups;

#define N_NODES  100000
#define N_EDGES  1600000
#define IN_CH    128
#define HID      32
#define N_GRAPHS 64

#define NBIN   391            // bins of 256 dst nodes: bin = dst >> 8
#define CHUNK  4096           // edges per build block; grid = 391
#define MGRID  391            // ceil(1.6M / 4096)
#define STG    5120           // phase-4 per-bin staging capacity
#define LCAP   2048           // layer_kernel LDS index staging capacity (8 KB)

// workspace layout (4-byte element offsets) — total ~26.4 MB
#define OFF_B      0          // bf16[3,200,000] packed as uint[1,600,000]; H[391*391] aliases head
#define OFF_EDGEPK 3200000    // int[1,600,000]; gsum/cnt alias after build
#define OFF_CSR    4800000    // int[1,600,000]
#define OFF_COLT   6400000    // int[391]
#define OFF_BINB   6400391    // int[392]
#define OFF_ROWPTR 6400784    // int[100,001]
#define OFF_DINV   6500785    // float[100,000]

// bf16 pack (RNE) / unpack helpers
__device__ __forceinline__ unsigned bfr(float f) {
    unsigned u = __float_as_uint(f);
    u += 0x7fffu + ((u >> 16) & 1u);
    return u >> 16;
}
__device__ __forceinline__ float bflo(unsigned w) { return __uint_as_float(w << 16); }
__device__ __forceinline__ float bfhi(unsigned w) { return __uint_as_float(w & 0xffff0000u); }

// ---------- fused CSR build: hist -> scanrow -> scanbase -> msplit -> csr2 ----------
// One cooperative kernel, 391 blocks x 512 threads; grid.sync() replaces the 4
// kernel boundaries (each of which was a full GPU drain + launch). Phase bodies
// are verbatim ports of the previously verified kernels. ~40KB LDS/block.
__global__ __launch_bounds__(512) void build_kernel(const int* __restrict__ src,
                                                    const int* __restrict__ dst,
                                                    int* __restrict__ H,
                                                    int* __restrict__ colT,
                                                    int* __restrict__ binB,
                                                    int* __restrict__ row_ptr,
                                                    float* __restrict__ dinv,
                                                    int* __restrict__ edgepk,
                                                    int* __restrict__ csr) {
    __shared__ int s[512];              // phase-1 hist (persists into phase 3)
    __shared__ int s2[512];             // scan scratch (phases 2a/2b/4)
    __shared__ int curA[NBIN];          // cursors (ph3) / counts (ph4)
    __shared__ int gb[NBIN];            // global bases (ph3) / cursors (ph4)
    __shared__ int shpool[2 * CHUNK];   // 32KB: stage+gof (ph3) / stage (ph4, STG<=8192)
    cg::grid_group grid = cg::this_grid();
    int t = threadIdx.x, wg = blockIdx.x;

    // ---- phase 1: per-(bin, wg) histogram ----
    s[t] = 0;
    __syncthreads();
    int e0 = wg * CHUNK, e1 = min(e0 + CHUNK, N_EDGES);
    for (int e = e0 + t; e < e1; e += 512) {
        int d = dst[e];
        if ((unsigned)d < N_NODES) atomicAdd(&s[d >> 8], 1);
    }
    __syncthreads();
    if (t < NBIN) H[t * MGRID + wg] = s[t];
    grid.sync();

    // ---- phase 2a: per-bin prefix over workgroups (bin = wg) ----
    s2[t] = (t < MGRID) ? H[wg * MGRID + t] : 0;
    __syncthreads();
    for (int off = 1; off < 512; off <<= 1) {
        int v = (t >= off) ? s2[t - off] : 0;
        __syncthreads();
        if (t >= off) s2[t] += v;
        __syncthreads();
    }
    if (t < MGRID) H[wg * MGRID + t] = t ? s2[t - 1] : 0;
    if (t == 0) colT[wg] = s2[MGRID - 1];
    grid.sync();

    // ---- phase 2b: bin-base scan (block 0 only) ----
    if (wg == 0) {
        s2[t] = (t < NBIN) ? colT[t] : 0;
        __syncthreads();
        for (int off = 1; off < 512; off <<= 1) {
            int v = (t >= off) ? s2[t - off] : 0;
            __syncthreads();
            if (t >= off) s2[t] += v;
            __syncthreads();
        }
        if (t < NBIN) binB[t] = t ? s2[t - 1] : 0;
        if (t == 0) { binB[NBIN] = s2[NBIN - 1]; row_ptr[N_NODES] = s2[NBIN - 1]; }
    }
    grid.sync();

    // ---- phase 3: bin-grouped scatter (s still holds this block's hist) ----
    for (int off = 1; off < 512; off <<= 1) {
        int v = (t >= off) ? s[t - off] : 0;
        __syncthreads();
        if (t >= off) s[t] += v;
        __syncthreads();
    }
    if (t < NBIN) {
        int lo = t ? s[t - 1] : 0;
        curA[t] = lo;
        gb[t] = binB[t] + H[t * MGRID + wg] - lo;
    }
    __syncthreads();
    int* stage = shpool;                // [CHUNK]
    int* gof   = shpool + CHUNK;        // [CHUNK]
    for (int e = e0 + t; e < e1; e += 512) {
        int d = dst[e];
        if ((unsigned)d < N_NODES) {
            int b = d >> 8;
            int p = atomicAdd(&curA[b], 1);
            stage[p] = (src[e] << 8) | (d & 255);
            gof[p] = gb[b];
        }
    }
    __syncthreads();
    int total = s[511];
    for (int p = t; p < total; p += 512)
        edgepk[gof[p] + p] = stage[p];
    grid.sync();

    // ---- phase 4: within-bin reorder -> CSR + dinv/row_ptr (bin = wg, 512 thr) ----
    int ebase = binB[wg], eend = binB[wg + 1];
    int n = eend - ebase;
    if (t < 256) curA[t] = 0;
    __syncthreads();
    for (int p = ebase + t; p < eend; p += 512)
        atomicAdd(&curA[edgepk[p] & 255], 1);
    __syncthreads();
    if (t < 256) s2[t] = curA[t];
    __syncthreads();
    for (int off = 1; off < 256; off <<= 1) {
        int v = (t >= off && t < 256) ? s2[t - off] : 0;
        __syncthreads();
        if (t >= off && t < 256) s2[t] += v;
        __syncthreads();
    }
    if (t < 256) {
        int excl = t ? s2[t - 1] : 0;
        int node = (wg << 8) + t;
        if (node < N_NODES) {
            dinv[node] = rsqrtf((float)(curA[t] + 1));
            row_ptr[node] = ebase + excl;
        }
        gb[t] = excl;
    }
    __syncthreads();
    for (int p = ebase + t; p < eend; p += 512) {
        int w = edgepk[p];
        int l = atomicAdd(&gb[w & 255], 1);
        int sv = w >> 8;
        if (l < STG) shpool[l] = sv;
        else csr[ebase + l] = sv;
    }
    __syncthreads();
    int lim = min(n, STG);
    for (int l = t; l < lim; l += 512)
        csr[ebase + l] = shpool[l];
}

// ---------- B(bf16) = (x @ W1) * dinv[row], register-tiled (4 ch/thread) ----------
// block 0 also zeroes gsum/cnt (aliased edgepk head, dead after build).
#define XS1 132               // 128 + 4 pad
__global__ __launch_bounds__(256) void gemm1_kernel(const float* __restrict__ x,
                                                    const float* __restrict__ W1,
                                                    const float* __restrict__ dinv,
                                                    unsigned* __restrict__ Bu,
                                                    float* __restrict__ gz) {
    __shared__ float Wl[IN_CH * HID];   // 16 KB
    __shared__ float xs[32 * XS1];      // 16.9 KB
    int tid = threadIdx.x;
    if (blockIdx.x == 0)
        for (int q = tid; q < N_GRAPHS * HID + N_GRAPHS; q += 256) gz[q] = 0.f;
    for (int j = tid; j < IN_CH * HID / 4; j += 256)
        ((float4*)Wl)[j] = ((const float4*)W1)[j];
    int row0 = blockIdx.x * 32;         // 100000 % 32 == 0
    const float4* x4 = (const float4*)(x + (size_t)row0 * IN_CH);
    for (int j = tid; j < 32 * IN_CH / 4; j += 256) {
        int r = j >> 5, k4 = j & 31;
        ((float4*)&xs[r * XS1])[k4] = x4[j];
    }
    __syncthreads();
    int r = tid >> 3, cg_ = (tid & 7) * 4;
    const float* xr = &xs[r * XS1];
    float4 acc = {0.f, 0.f, 0.f, 0.f};
    #pragma unroll 8
    for (int k = 0; k < IN_CH; ++k) {
        float xv = xr[k];
        float4 w = *(const float4*)&Wl[k * HID + cg_];
        acc.x += xv * w.x; acc.y += xv * w.y; acc.z += xv * w.z; acc.w += xv * w.w;
    }
    int row = row0 + r;
    float dv = dinv[row];
    uint2 p;
    p.x = bfr(acc.x * dv) | (bfr(acc.y * dv) << 16);
    p.y = bfr(acc.z * dv) | (bfr(acc.w * dv) << 16);
    *(uint2*)&Bu[(size_t)row * 16 + (tid & 7) * 2] = p;
}

// ---------- B(bf16) = (in @ W2) * dinv[row], register-tiled ----------
#define XS2 36                // 32 + 4 pad
__global__ __launch_bounds__(256) void gemm2_kernel(const float* __restrict__ in,
                                                    const float* __restrict__ W2,
                                                    const float* __restrict__ dinv,
                                                    unsigned* __restrict__ Bu) {
    __shared__ float Wl[HID * HID];     // 4 KB
    __shared__ float xs[32 * XS2];      // 4.6 KB
    int tid = threadIdx.x;
    ((float4*)Wl)[tid] = ((const float4*)W2)[tid];
    int row0 = blockIdx.x * 32;
    const float4* in4 = (const float4*)(in + (size_t)row0 * HID);
    {
        int r = tid >> 3, k4 = tid & 7;
        ((float4*)&xs[r * XS2])[k4] = in4[tid];
    }
    __syncthreads();
    int r = tid >> 3, cg_ = (tid & 7) * 4;
    const float* xr = &xs[r * XS2];
    float4 acc = {0.f, 0.f, 0.f, 0.f};
    #pragma unroll
    for (int k = 0; k < HID; ++k) {
        float xv = xr[k];
        float4 w = *(const float4*)&Wl[k * HID + cg_];
        acc.x += xv * w.x; acc.y += xv * w.y; acc.z += xv * w.z; acc.w += xv * w.w;
    }
    int row = row0 + r;
    float dv = dinv[row];
    uint2 p;
    p.x = bfr(acc.x * dv) | (bfr(acc.y * dv) << 16);
    p.y = bfr(acc.z * dv) | (bfr(acc.w * dv) << 16);
    *(uint2*)&Bu[(size_t)row * 16 + (tid & 7) * 2] = p;
}

// ---------- gather layer: LDS-staged indices + uint4 Bu gathers (R6-proven) ----------
__global__ __launch_bounds__(256) void layer_kernel(const unsigned* __restrict__ Bu,
                                                    const int* __restrict__ csr,
                                                    const int* __restrict__ row_ptr,
                                                    const float* __restrict__ dinv,
                                                    const float* __restrict__ bias,
                                                    float* __restrict__ out,
                                                    int relu) {
    __shared__ int sidx[LCAP];          // 8 KB
    int tid = threadIdx.x;
    int n0 = blockIdx.x * 64;           // grid 1563, tail guarded
    int nend = min(n0 + 64, N_NODES);
    int j0 = row_ptr[n0], j1 = row_ptr[nend];
    int nblk = j1 - j0;
    int staged = (nblk <= LCAP);
    if (staged)
        for (int p = tid; p < nblk; p += 256) sidx[p] = csr[j0 + p];
    __syncthreads();
    int node = n0 + (tid >> 2);
    if (node >= N_NODES) return;
    int c4 = tid & 3;                   // owns channels 8*c4 .. 8*c4+7
    const uint4* Br = (const uint4*)Bu; // 4 uint4 per node row
    uint4 sw = Br[(size_t)node * 4 + c4];   // self-loop term
    float a0 = bflo(sw.x), a1 = bfhi(sw.x);
    float a2 = bflo(sw.y), a3 = bfhi(sw.y);
    float a4 = bflo(sw.z), a5 = bfhi(sw.z);
    float a6 = bflo(sw.w), a7 = bfhi(sw.w);
    if (staged) {
        int j = row_ptr[node] - j0, re = row_ptr[node + 1] - j0;
        for (; j + 8 <= re; j += 8) {
            int s0 = sidx[j + 0], s1 = sidx[j + 1], s2 = sidx[j + 2], s3 = sidx[j + 3];
            int s4 = sidx[j + 4], s5 = sidx[j + 5], s6 = sidx[j + 6], s7 = sidx[j + 7];
            uint4 w0 = Br[(size_t)s0 * 4 + c4], w1 = Br[(size_t)s1 * 4 + c4];
            uint4 w2 = Br[(size_t)s2 * 4 + c4], w3 = Br[(size_t)s3 * 4 + c4];
            uint4 w4 = Br[(size_t)s4 * 4 + c4], w5 = Br[(size_t)s5 * 4 + c4];
            uint4 w6 = Br[(size_t)s6 * 4 + c4], w7 = Br[(size_t)s7 * 4 + c4];
            a0 += ((bflo(w0.x) + bflo(w1.x)) + (bflo(w2.x) + bflo(w3.x)))
                + ((bflo(w4.x) + bflo(w5.x)) + (bflo(w6.x) + bflo(w7.x)));
            a1 += ((bfhi(w0.x) + bfhi(w1.x)) + (bfhi(w2.x) + bfhi(w3.x)))
                + ((bfhi(w4.x) + bfhi(w5.x)) + (bfhi(w6.x) + bfhi(w7.x)));
            a2 += ((bflo(w0.y) + bflo(w1.y)) + (bflo(w2.y) + bflo(w3.y)))
                + ((bflo(w4.y) + bflo(w5.y)) + (bflo(w6.y) + bflo(w7.y)));
            a3 += ((bfhi(w0.y) + bfhi(w1.y)) + (bfhi(w2.y) + bfhi(w3.y)))
                + ((bfhi(w4.y) + bfhi(w5.y)) + (bfhi(w6.y) + bfhi(w7.y)));
            a4 += ((bflo(w0.z) + bflo(w1.z)) + (bflo(w2.z) + bflo(w3.z)))
                + ((bflo(w4.z) + bflo(w5.z)) + (bflo(w6.z) + bflo(w7.z)));
            a5 += ((bfhi(w0.z) + bfhi(w1.z)) + (bfhi(w2.z) + bfhi(w3.z)))
                + ((bfhi(w4.z) + bfhi(w5.z)) + (bfhi(w6.z) + bfhi(w7.z)));
            a6 += ((bflo(w0.w) + bflo(w1.w)) + (bflo(w2.w) + bflo(w3.w)))
                + ((bflo(w4.w) + bflo(w5.w)) + (bflo(w6.w) + bflo(w7.w)));
            a7 += ((bfhi(w0.w) + bfhi(w1.w)) + (bfhi(w2.w) + bfhi(w3.w)))
                + ((bfhi(w4.w) + bfhi(w5.w)) + (bfhi(w6.w) + bfhi(w7.w)));
        }
        if (j + 4 <= re) {
            int s0 = sidx[j], s1 = sidx[j + 1], s2 = sidx[j + 2], s3 = sidx[j + 3];
            uint4 w0 = Br[(size_t)s0 * 4 + c4], w1 = Br[(size_t)s1 * 4 + c4];
            uint4 w2 = Br[(size_t)s2 * 4 + c4], w3 = Br[(size_t)s3 * 4 + c4];
            a0 += (bflo(w0.x) + bflo(w1.x)) + (bflo(w2.x) + bflo(w3.x));
            a1 += (bfhi(w0.x) + bfhi(w1.x)) + (bfhi(w2.x) + bfhi(w3.x));
            a2 += (bflo(w0.y) + bflo(w1.y)) + (bflo(w2.y) + bflo(w3.y));
            a3 += (bfhi(w0.y) + bfhi(w1.y)) + (bfhi(w2.y) + bfhi(w3.y));
            a4 += (bflo(w0.z) + bflo(w1.z)) + (bflo(w2.z) + bflo(w3.z));
            a5 += (bfhi(w0.z) + bfhi(w1.z)) + (bfhi(w2.z) + bfhi(w3.z));
            a6 += (bflo(w0.w) + bflo(w1.w)) + (bflo(w2.w) + bflo(w3.w));
            a7 += (bfhi(w0.w) + bfhi(w1.w)) + (bfhi(w2.w) + bfhi(w3.w));
            j += 4;
        }
        for (; j < re; ++j) {
            uint4 w = Br[(size_t)sidx[j] * 4 + c4];
            a0 += bflo(w.x); a1 += bfhi(w.x);
            a2 += bflo(w.y); a3 += bfhi(w.y);
            a4 += bflo(w.z); a5 += bfhi(w.z);
            a6 += bflo(w.w); a7 += bfhi(w.w);
        }
    } else {
        int j = row_ptr[node], re = row_ptr[node + 1];
        for (; j < re; ++j) {
            uint4 w = Br[(size_t)csr[j] * 4 + c4];
            a0 += bflo(w.x); a1 += bfhi(w.x);
            a2 += bflo(w.y); a3 += bfhi(w.y);
            a4 += bflo(w.z); a5 += bfhi(w.z);
            a6 += bflo(w.w); a7 += bfhi(w.w);
        }
    }
    float dv = dinv[node];
    float4 bA = *(const float4*)&bias[8 * c4];
    float4 bB = *(const float4*)&bias[8 * c4 + 4];
    float4 o1, o2;
    o1.x = a0 * dv + bA.x; o1.y = a1 * dv + bA.y;
    o1.z = a2 * dv + bA.z; o1.w = a3 * dv + bA.w;
    o2.x = a4 * dv + bB.x; o2.y = a5 * dv + bB.y;
    o2.z = a6 * dv + bB.z; o2.w = a7 * dv + bB.w;
    if (relu) {
        o1.x = fmaxf(o1.x, 0.f); o1.y = fmaxf(o1.y, 0.f);
        o1.z = fmaxf(o1.z, 0.f); o1.w = fmaxf(o1.w, 0.f);
        o2.x = fmaxf(o2.x, 0.f); o2.y = fmaxf(o2.y, 0.f);
        o2.z = fmaxf(o2.z, 0.f); o2.w = fmaxf(o2.w, 0.f);
    }
    float* orow = out + (size_t)node * HID + 8 * c4;
    *(float4*)orow = o1;
    *(float4*)(orow + 4) = o2;
}

// ---------- per-graph mean-pool: register run-accumulation + span flush ----------
__global__ __launch_bounds__(256) void pool_kernel(const float* __restrict__ h,
                                                   const int* __restrict__ batch,
                                                   float* __restrict__ gsum,
                                                   float* __restrict__ cnt) {
    __shared__ float pool[N_GRAPHS * HID];  // 8 KB
    __shared__ float cntl[N_GRAPHS];
    __shared__ int gmin, gmax;
    int t = threadIdx.x;
    for (int j = t; j < N_GRAPHS * HID; j += 256) pool[j] = 0.f;
    if (t < N_GRAPHS) cntl[t] = 0.f;
    if (t == 0) { gmin = N_GRAPHS; gmax = -1; }
    __syncthreads();
    int start = blockIdx.x * 256;
    int end = min(start + 256, N_NODES);
    int c = t & 31;
    float racc = 0.f;
    int rg = -1, rcnt = 0;
    for (int nb = start + (t >> 5); nb < end; nb += 8) {
        float v = h[(size_t)nb * HID + c];
        int g = batch[nb];
        if (g != rg) {
            if ((unsigned)rg < N_GRAPHS) {
                atomicAdd(&pool[rg * HID + c], racc);
                if (c == 0) {
                    atomicAdd(&cntl[rg], (float)rcnt);
                    atomicMin(&gmin, rg); atomicMax(&gmax, rg);
                }
            }
            rg = g; racc = v; rcnt = 1;
        } else { racc += v; ++rcnt; }
    }
    if ((unsigned)rg < N_GRAPHS) {
        atomicAdd(&pool[rg * HID + c], racc);
        if (c == 0) {
            atomicAdd(&cntl[rg], (float)rcnt);
            atomicMin(&gmin, rg); atomicMax(&gmax, rg);
        }
    }
    __syncthreads();
    int lo = gmin, hi = gmax;
    if (hi >= lo) {
        int span = (hi - lo + 1) * HID;
        for (int j = t; j < span; j += 256)
            atomicAdd(&gsum[lo * HID + j], pool[lo * HID + j]);
        for (int j = t; j <= hi - lo; j += 256)
            atomicAdd(&cnt[lo + j], cntl[lo + j]);
    }
}

__global__ void summary_kernel(const float* __restrict__ gsum, const float* __restrict__ cnt,
                               const float* __restrict__ Ws, const float* __restrict__ bs,
                               float* __restrict__ out) {
    int g = blockIdx.x, c = threadIdx.x;
    float inv = 1.f / fmaxf(cnt[g], 1.f);
    float acc = bs[c];
    #pragma unroll
    for (int k = 0; k < HID; ++k)
        acc += gsum[g * HID + k] * inv * Ws[k * HID + c];
    out[g * HID + c] = acc;
}

extern "C" void kernel_launch(void* const* d_in, const int* in_sizes, int n_in,
                              void* d_out, int out_size, void* d_ws, size_t ws_size,
                              hipStream_t stream) {
    const float* x    = (const float*)d_in[0];
    const int* edge   = (const int*)d_in[1];
    const int* src    = edge;
    const int* dst    = edge + N_EDGES;
    const int* batch  = (const int*)d_in[2];
    const float* W1   = (const float*)d_in[3];
    const float* b1   = (const float*)d_in[4];
    const float* W2   = (const float*)d_in[5];
    const float* b2   = (const float*)d_in[6];
    const float* Ws   = (const float*)d_in[7];
    const float* bs   = (const float*)d_in[8];

    float* ws      = (float*)d_ws;
    unsigned* Bu   = (unsigned*)(ws + OFF_B);   // bf16-packed B
    int*   H       = (int*)(ws + OFF_B);        // aliases B head; dead before gemm1
    int*   edgepk  = (int*)(ws + OFF_EDGEPK);
    int*   csr     = (int*)(ws + OFF_CSR);
    int*   colT    = (int*)(ws + OFF_COLT);
    int*   binB    = (int*)(ws + OFF_BINB);
    int*   row_ptr = (int*)(ws + OFF_ROWPTR);
    float* dinv    = ws + OFF_DINV;
    float* gsum    = ws + OFF_EDGEPK;           // aliases edgepk (dead after build)
    float* cnt     = gsum + N_GRAPHS * HID;

    float* out     = (float*)d_out;
    float* out_sum = out;
    float* out_h   = out + N_GRAPHS * HID;

    // fused CSR build (cooperative: 4 grid syncs replace 4 kernel boundaries)
    void* bargs[] = { (void*)&src, (void*)&dst, (void*)&H, (void*)&colT,
                      (void*)&binB, (void*)&row_ptr, (void*)&dinv,
                      (void*)&edgepk, (void*)&csr };
    hipLaunchCooperativeKernel((const void*)build_kernel, dim3(MGRID), dim3(512),
                               bargs, 0, stream);

    int lgrid = (N_NODES + 63) / 64;   // 1563

    // layer 1 (gemm1 block 0 zeroes gsum/cnt)
    gemm1_kernel<<<N_NODES / 32, 256, 0, stream>>>(x, W1, dinv, Bu, gsum);
    layer_kernel<<<lgrid, 256, 0, stream>>>(Bu, csr, row_ptr, dinv, b1, out_h, 1);

    // layer 2
    gemm2_kernel<<<N_NODES / 32, 256, 0, stream>>>(out_h, W2, dinv, Bu);
    layer_kernel<<<lgrid, 256, 0, stream>>>(Bu, csr, row_ptr, dinv, b2, out_h, 0);

    // pooling + summary
    pool_kernel<<<NBIN, 256, 0, stream>>>(out_h, batch, gsum, cnt);
    summary_kernel<<<N_GRAPHS, HID, 0, stream>>>(gsum, cnt, Ws, bs, out_sum);
}

// Round 9
// 355.834 us; speedup vs baseline: 1.2129x; 1.2129x over previous
//
#include <hip/hip_runtime.h>

#define N_NODES  100000
#define N_EDGES  1600000
#define IN_CH    128
#define HID      32
#define N_GRAPHS 64

#define LCAP   2048           // layer_kernel LDS index staging capacity (8 KB)
#define NB256  391            // ceil(100000/256)

// workspace layout (4-byte element offsets)
#define OFF_B      0          // bf16 B, uint[1,600,000]
#define OFF_CSR    1600000    // int[1,600,000] (dense CSR)
#define OFF_DEG    3200000    // int[100,000]
#define OFF_CUR    3300000    // int[100,000]   (deg+cur zeroed in one memset)
#define OFF_RPL    3400000    // int[100,000]   (within-256-chunk prefix)
#define OFF_ROWPTR 3500000    // int[100,001]
#define OFF_DINV   3600001    // float[100,000]
#define OFF_BINT   3700001    // int[392]       (chunk totals -> chunk bases)
#define OFF_GS     3701000    // float[64*32] gsum + float[64] cnt

// bf16 pack (RNE) / unpack helpers
__device__ __forceinline__ unsigned bfr(float f) {
    unsigned u = __float_as_uint(f);
    u += 0x7fffu + ((u >> 16) & 1u);
    return u >> 16;
}
__device__ __forceinline__ float bflo(unsigned w) { return __uint_as_float(w << 16); }
__device__ __forceinline__ float bfhi(unsigned w) { return __uint_as_float(w & 0xffff0000u); }

// ---------- build 1: degree histogram (coalesced read, L2-resident atomics) ----------
__global__ __launch_bounds__(256) void deg_kernel(const int* __restrict__ dst,
                                                  int* __restrict__ deg) {
    int e = blockIdx.x * 256 + threadIdx.x;   // grid 6250 -> exactly 1.6M
    int d = dst[e];
    if ((unsigned)d < N_NODES) atomicAdd(&deg[d], 1);
}

// ---------- build 2a: per-256-chunk exclusive scan of deg ----------
__global__ __launch_bounds__(256) void scan1_kernel(const int* __restrict__ deg,
                                                    int* __restrict__ rpl,
                                                    int* __restrict__ binT) {
    __shared__ int s[256];
    int t = threadIdx.x, b = blockIdx.x;
    int node = b * 256 + t;
    int v = (node < N_NODES) ? deg[node] : 0;
    s[t] = v;
    __syncthreads();
    for (int off = 1; off < 256; off <<= 1) {
        int u = (t >= off) ? s[t - off] : 0;
        __syncthreads();
        if (t >= off) s[t] += u;
        __syncthreads();
    }
    if (node < N_NODES) rpl[node] = s[t] - v;
    if (t == 255) binT[b] = s[255];
}

// ---------- build 2b: scan the 391 chunk totals ----------
__global__ __launch_bounds__(512) void scan2_kernel(int* __restrict__ binT,
                                                    int* __restrict__ row_ptr) {
    __shared__ int s[512];
    int t = threadIdx.x;
    s[t] = (t < NB256) ? binT[t] : 0;
    __syncthreads();
    for (int off = 1; off < 512; off <<= 1) {
        int v = (t >= off) ? s[t - off] : 0;
        __syncthreads();
        if (t >= off) s[t] += v;
        __syncthreads();
    }
    if (t < NB256) binT[t] = t ? s[t - 1] : 0;
    if (t == 0) row_ptr[N_NODES] = s[NB256 - 1];
}

// ---------- build 2c: absolute row_ptr + dinv ----------
__global__ __launch_bounds__(256) void scan3_kernel(const int* __restrict__ deg,
                                                    const int* __restrict__ rpl,
                                                    const int* __restrict__ binT,
                                                    int* __restrict__ row_ptr,
                                                    float* __restrict__ dinv) {
    int node = blockIdx.x * 256 + threadIdx.x;
    if (node >= N_NODES) return;
    row_ptr[node] = binT[node >> 8] + rpl[node];
    dinv[node] = rsqrtf((float)(deg[node] + 1));
}

// ---------- build 3: direct scatter into dense CSR ----------
__global__ __launch_bounds__(256) void scatter_kernel(const int* __restrict__ src,
                                                      const int* __restrict__ dst,
                                                      const int* __restrict__ row_ptr,
                                                      int* __restrict__ cur,
                                                      int* __restrict__ csr) {
    int e = blockIdx.x * 256 + threadIdx.x;   // grid 6250
    int d = dst[e];
    if ((unsigned)d >= N_NODES) return;
    int s = src[e];
    int p = atomicAdd(&cur[d], 1);
    csr[row_ptr[d] + p] = s;
}

// ---------- B(bf16) = (x @ W1) * dinv[row], register-tiled (4 ch/thread) ----------
// block 0 also zeroes gsum/cnt.
#define XS1 132               // 128 + 4 pad
__global__ __launch_bounds__(256) void gemm1_kernel(const float* __restrict__ x,
                                                    const float* __restrict__ W1,
                                                    const float* __restrict__ dinv,
                                                    unsigned* __restrict__ Bu,
                                                    float* __restrict__ gz) {
    __shared__ float Wl[IN_CH * HID];   // 16 KB
    __shared__ float xs[32 * XS1];      // 16.9 KB
    int tid = threadIdx.x;
    if (blockIdx.x == 0)
        for (int q = tid; q < N_GRAPHS * HID + N_GRAPHS; q += 256) gz[q] = 0.f;
    for (int j = tid; j < IN_CH * HID / 4; j += 256)
        ((float4*)Wl)[j] = ((const float4*)W1)[j];
    int row0 = blockIdx.x * 32;         // 100000 % 32 == 0
    const float4* x4 = (const float4*)(x + (size_t)row0 * IN_CH);
    for (int j = tid; j < 32 * IN_CH / 4; j += 256) {
        int r = j >> 5, k4 = j & 31;
        ((float4*)&xs[r * XS1])[k4] = x4[j];
    }
    __syncthreads();
    int r = tid >> 3, cg = (tid & 7) * 4;
    const float* xr = &xs[r * XS1];
    float4 acc = {0.f, 0.f, 0.f, 0.f};
    #pragma unroll 8
    for (int k = 0; k < IN_CH; ++k) {
        float xv = xr[k];
        float4 w = *(const float4*)&Wl[k * HID + cg];
        acc.x += xv * w.x; acc.y += xv * w.y; acc.z += xv * w.z; acc.w += xv * w.w;
    }
    int row = row0 + r;
    float dv = dinv[row];
    uint2 p;
    p.x = bfr(acc.x * dv) | (bfr(acc.y * dv) << 16);
    p.y = bfr(acc.z * dv) | (bfr(acc.w * dv) << 16);
    *(uint2*)&Bu[(size_t)row * 16 + (tid & 7) * 2] = p;
}

// ---------- B(bf16) = (in @ W2) * dinv[row], register-tiled ----------
#define XS2 36                // 32 + 4 pad
__global__ __launch_bounds__(256) void gemm2_kernel(const float* __restrict__ in,
                                                    const float* __restrict__ W2,
                                                    const float* __restrict__ dinv,
                                                    unsigned* __restrict__ Bu) {
    __shared__ float Wl[HID * HID];     // 4 KB
    __shared__ float xs[32 * XS2];      // 4.6 KB
    int tid = threadIdx.x;
    ((float4*)Wl)[tid] = ((const float4*)W2)[tid];
    int row0 = blockIdx.x * 32;
    const float4* in4 = (const float4*)(in + (size_t)row0 * HID);
    {
        int r = tid >> 3, k4 = tid & 7;
        ((float4*)&xs[r * XS2])[k4] = in4[tid];
    }
    __syncthreads();
    int r = tid >> 3, cg = (tid & 7) * 4;
    const float* xr = &xs[r * XS2];
    float4 acc = {0.f, 0.f, 0.f, 0.f};
    #pragma unroll
    for (int k = 0; k < HID; ++k) {
        float xv = xr[k];
        float4 w = *(const float4*)&Wl[k * HID + cg];
        acc.x += xv * w.x; acc.y += xv * w.y; acc.z += xv * w.z; acc.w += xv * w.w;
    }
    int row = row0 + r;
    float dv = dinv[row];
    uint2 p;
    p.x = bfr(acc.x * dv) | (bfr(acc.y * dv) << 16);
    p.y = bfr(acc.z * dv) | (bfr(acc.w * dv) << 16);
    *(uint2*)&Bu[(size_t)row * 16 + (tid & 7) * 2] = p;
}

// ---------- gather layer: LDS-staged indices + uint4 Bu gathers (R6-proven) ----------
__global__ __launch_bounds__(256) void layer_kernel(const unsigned* __restrict__ Bu,
                                                    const int* __restrict__ csr,
                                                    const int* __restrict__ row_ptr,
                                                    const float* __restrict__ dinv,
                                                    const float* __restrict__ bias,
                                                    float* __restrict__ out,
                                                    int relu) {
    __shared__ int sidx[LCAP];          // 8 KB
    int tid = threadIdx.x;
    int n0 = blockIdx.x * 64;           // grid 1563, tail guarded
    int nend = min(n0 + 64, N_NODES);
    int j0 = row_ptr[n0], j1 = row_ptr[nend];
    int nblk = j1 - j0;
    int staged = (nblk <= LCAP);
    if (staged)
        for (int p = tid; p < nblk; p += 256) sidx[p] = csr[j0 + p];
    __syncthreads();
    int node = n0 + (tid >> 2);
    if (node >= N_NODES) return;
    int c4 = tid & 3;                   // owns channels 8*c4 .. 8*c4+7
    const uint4* Br = (const uint4*)Bu; // 4 uint4 per node row
    uint4 sw = Br[(size_t)node * 4 + c4];   // self-loop term
    float a0 = bflo(sw.x), a1 = bfhi(sw.x);
    float a2 = bflo(sw.y), a3 = bfhi(sw.y);
    float a4 = bflo(sw.z), a5 = bfhi(sw.z);
    float a6 = bflo(sw.w), a7 = bfhi(sw.w);
    if (staged) {
        int j = row_ptr[node] - j0, re = row_ptr[node + 1] - j0;
        for (; j + 8 <= re; j += 8) {
            int s0 = sidx[j + 0], s1 = sidx[j + 1], s2 = sidx[j + 2], s3 = sidx[j + 3];
            int s4 = sidx[j + 4], s5 = sidx[j + 5], s6 = sidx[j + 6], s7 = sidx[j + 7];
            uint4 w0 = Br[(size_t)s0 * 4 + c4], w1 = Br[(size_t)s1 * 4 + c4];
            uint4 w2 = Br[(size_t)s2 * 4 + c4], w3 = Br[(size_t)s3 * 4 + c4];
            uint4 w4 = Br[(size_t)s4 * 4 + c4], w5 = Br[(size_t)s5 * 4 + c4];
            uint4 w6 = Br[(size_t)s6 * 4 + c4], w7 = Br[(size_t)s7 * 4 + c4];
            a0 += ((bflo(w0.x) + bflo(w1.x)) + (bflo(w2.x) + bflo(w3.x)))
                + ((bflo(w4.x) + bflo(w5.x)) + (bflo(w6.x) + bflo(w7.x)));
            a1 += ((bfhi(w0.x) + bfhi(w1.x)) + (bfhi(w2.x) + bfhi(w3.x)))
                + ((bfhi(w4.x) + bfhi(w5.x)) + (bfhi(w6.x) + bfhi(w7.x)));
            a2 += ((bflo(w0.y) + bflo(w1.y)) + (bflo(w2.y) + bflo(w3.y)))
                + ((bflo(w4.y) + bflo(w5.y)) + (bflo(w6.y) + bflo(w7.y)));
            a3 += ((bfhi(w0.y) + bfhi(w1.y)) + (bfhi(w2.y) + bfhi(w3.y)))
                + ((bfhi(w4.y) + bfhi(w5.y)) + (bfhi(w6.y) + bfhi(w7.y)));
            a4 += ((bflo(w0.z) + bflo(w1.z)) + (bflo(w2.z) + bflo(w3.z)))
                + ((bflo(w4.z) + bflo(w5.z)) + (bflo(w6.z) + bflo(w7.z)));
            a5 += ((bfhi(w0.z) + bfhi(w1.z)) + (bfhi(w2.z) + bfhi(w3.z)))
                + ((bfhi(w4.z) + bfhi(w5.z)) + (bfhi(w6.z) + bfhi(w7.z)));
            a6 += ((bflo(w0.w) + bflo(w1.w)) + (bflo(w2.w) + bflo(w3.w)))
                + ((bflo(w4.w) + bflo(w5.w)) + (bflo(w6.w) + bflo(w7.w)));
            a7 += ((bfhi(w0.w) + bfhi(w1.w)) + (bfhi(w2.w) + bfhi(w3.w)))
                + ((bfhi(w4.w) + bfhi(w5.w)) + (bfhi(w6.w) + bfhi(w7.w)));
        }
        if (j + 4 <= re) {
            int s0 = sidx[j], s1 = sidx[j + 1], s2 = sidx[j + 2], s3 = sidx[j + 3];
            uint4 w0 = Br[(size_t)s0 * 4 + c4], w1 = Br[(size_t)s1 * 4 + c4];
            uint4 w2 = Br[(size_t)s2 * 4 + c4], w3 = Br[(size_t)s3 * 4 + c4];
            a0 += (bflo(w0.x) + bflo(w1.x)) + (bflo(w2.x) + bflo(w3.x));
            a1 += (bfhi(w0.x) + bfhi(w1.x)) + (bfhi(w2.x) + bfhi(w3.x));
            a2 += (bflo(w0.y) + bflo(w1.y)) + (bflo(w2.y) + bflo(w3.y));
            a3 += (bfhi(w0.y) + bfhi(w1.y)) + (bfhi(w2.y) + bfhi(w3.y));
            a4 += (bflo(w0.z) + bflo(w1.z)) + (bflo(w2.z) + bflo(w3.z));
            a5 += (bfhi(w0.z) + bfhi(w1.z)) + (bfhi(w2.z) + bfhi(w3.z));
            a6 += (bflo(w0.w) + bflo(w1.w)) + (bflo(w2.w) + bflo(w3.w));
            a7 += (bfhi(w0.w) + bfhi(w1.w)) + (bfhi(w2.w) + bfhi(w3.w));
            j += 4;
        }
        for (; j < re; ++j) {
            uint4 w = Br[(size_t)sidx[j] * 4 + c4];
            a0 += bflo(w.x); a1 += bfhi(w.x);
            a2 += bflo(w.y); a3 += bfhi(w.y);
            a4 += bflo(w.z); a5 += bfhi(w.z);
            a6 += bflo(w.w); a7 += bfhi(w.w);
        }
    } else {
        int j = row_ptr[node], re = row_ptr[node + 1];
        for (; j < re; ++j) {
            uint4 w = Br[(size_t)csr[j] * 4 + c4];
            a0 += bflo(w.x); a1 += bfhi(w.x);
            a2 += bflo(w.y); a3 += bfhi(w.y);
            a4 += bflo(w.z); a5 += bfhi(w.z);
            a6 += bflo(w.w); a7 += bfhi(w.w);
        }
    }
    float dv = dinv[node];
    float4 bA = *(const float4*)&bias[8 * c4];
    float4 bB = *(const float4*)&bias[8 * c4 + 4];
    float4 o1, o2;
    o1.x = a0 * dv + bA.x; o1.y = a1 * dv + bA.y;
    o1.z = a2 * dv + bA.z; o1.w = a3 * dv + bA.w;
    o2.x = a4 * dv + bB.x; o2.y = a5 * dv + bB.y;
    o2.z = a6 * dv + bB.z; o2.w = a7 * dv + bB.w;
    if (relu) {
        o1.x = fmaxf(o1.x, 0.f); o1.y = fmaxf(o1.y, 0.f);
        o1.z = fmaxf(o1.z, 0.f); o1.w = fmaxf(o1.w, 0.f);
        o2.x = fmaxf(o2.x, 0.f); o2.y = fmaxf(o2.y, 0.f);
        o2.z = fmaxf(o2.z, 0.f); o2.w = fmaxf(o2.w, 0.f);
    }
    float* orow = out + (size_t)node * HID + 8 * c4;
    *(float4*)orow = o1;
    *(float4*)(orow + 4) = o2;
}

// ---------- per-graph mean-pool: register run-accumulation + span flush ----------
__global__ __launch_bounds__(256) void pool_kernel(const float* __restrict__ h,
                                                   const int* __restrict__ batch,
                                                   float* __restrict__ gsum,
                                                   float* __restrict__ cnt) {
    __shared__ float pool[N_GRAPHS * HID];  // 8 KB
    __shared__ float cntl[N_GRAPHS];
    __shared__ int gmin, gmax;
    int t = threadIdx.x;
    for (int j = t; j < N_GRAPHS * HID; j += 256) pool[j] = 0.f;
    if (t < N_GRAPHS) cntl[t] = 0.f;
    if (t == 0) { gmin = N_GRAPHS; gmax = -1; }
    __syncthreads();
    int start = blockIdx.x * 256;
    int end = min(start + 256, N_NODES);
    int c = t & 31;
    float racc = 0.f;
    int rg = -1, rcnt = 0;
    for (int nb = start + (t >> 5); nb < end; nb += 8) {
        float v = h[(size_t)nb * HID + c];
        int g = batch[nb];
        if (g != rg) {
            if ((unsigned)rg < N_GRAPHS) {
                atomicAdd(&pool[rg * HID + c], racc);
                if (c == 0) {
                    atomicAdd(&cntl[rg], (float)rcnt);
                    atomicMin(&gmin, rg); atomicMax(&gmax, rg);
                }
            }
            rg = g; racc = v; rcnt = 1;
        } else { racc += v; ++rcnt; }
    }
    if ((unsigned)rg < N_GRAPHS) {
        atomicAdd(&pool[rg * HID + c], racc);
        if (c == 0) {
            atomicAdd(&cntl[rg], (float)rcnt);
            atomicMin(&gmin, rg); atomicMax(&gmax, rg);
        }
    }
    __syncthreads();
    int lo = gmin, hi = gmax;
    if (hi >= lo) {
        int span = (hi - lo + 1) * HID;
        for (int j = t; j < span; j += 256)
            atomicAdd(&gsum[lo * HID + j], pool[lo * HID + j]);
        for (int j = t; j <= hi - lo; j += 256)
            atomicAdd(&cnt[lo + j], cntl[lo + j]);
    }
}

__global__ void summary_kernel(const float* __restrict__ gsum, const float* __restrict__ cnt,
                               const float* __restrict__ Ws, const float* __restrict__ bs,
                               float* __restrict__ out) {
    int g = blockIdx.x, c = threadIdx.x;
    float inv = 1.f / fmaxf(cnt[g], 1.f);
    float acc = bs[c];
    #pragma unroll
    for (int k = 0; k < HID; ++k)
        acc += gsum[g * HID + k] * inv * Ws[k * HID + c];
    out[g * HID + c] = acc;
}

extern "C" void kernel_launch(void* const* d_in, const int* in_sizes, int n_in,
                              void* d_out, int out_size, void* d_ws, size_t ws_size,
                              hipStream_t stream) {
    const float* x    = (const float*)d_in[0];
    const int* edge   = (const int*)d_in[1];
    const int* src    = edge;
    const int* dst    = edge + N_EDGES;
    const int* batch  = (const int*)d_in[2];
    const float* W1   = (const float*)d_in[3];
    const float* b1   = (const float*)d_in[4];
    const float* W2   = (const float*)d_in[5];
    const float* b2   = (const float*)d_in[6];
    const float* Ws   = (const float*)d_in[7];
    const float* bs   = (const float*)d_in[8];

    float* ws      = (float*)d_ws;
    unsigned* Bu   = (unsigned*)(ws + OFF_B);
    int*   csr     = (int*)(ws + OFF_CSR);
    int*   deg     = (int*)(ws + OFF_DEG);
    int*   cur     = (int*)(ws + OFF_CUR);
    int*   rpl     = (int*)(ws + OFF_RPL);
    int*   row_ptr = (int*)(ws + OFF_ROWPTR);
    float* dinv    = ws + OFF_DINV;
    int*   binT    = (int*)(ws + OFF_BINT);
    float* gsum    = ws + OFF_GS;
    float* cnt     = gsum + N_GRAPHS * HID;

    float* out     = (float*)d_out;
    float* out_sum = out;
    float* out_h   = out + N_GRAPHS * HID;

    // direct CSR build: deg -> scan -> scatter
    hipMemsetAsync(deg, 0, 2 * N_NODES * sizeof(int), stream);   // deg + cur
    deg_kernel   <<<N_EDGES / 256, 256, 0, stream>>>(dst, deg);
    scan1_kernel <<<NB256, 256, 0, stream>>>(deg, rpl, binT);
    scan2_kernel <<<1, 512, 0, stream>>>(binT, row_ptr);
    scan3_kernel <<<NB256, 256, 0, stream>>>(deg, rpl, binT, row_ptr, dinv);
    scatter_kernel<<<N_EDGES / 256, 256, 0, stream>>>(src, dst, row_ptr, cur, csr);

    int lgrid = (N_NODES + 63) / 64;   // 1563

    // layer 1 (gemm1 block 0 zeroes gsum/cnt)
    gemm1_kernel<<<N_NODES / 32, 256, 0, stream>>>(x, W1, dinv, Bu, gsum);
    layer_kernel<<<lgrid, 256, 0, stream>>>(Bu, csr, row_ptr, dinv, b1, out_h, 1);

    // layer 2
    gemm2_kernel<<<N_NODES / 32, 256, 0, stream>>>(out_h, W2, dinv, Bu);
    layer_kernel<<<lgrid, 256, 0, stream>>>(Bu, csr, row_ptr, dinv, b2, out_h, 0);

    // pooling + summary
    pool_kernel<<<NB256, 256, 0, stream>>>(out_h, batch, gsum, cnt);
    summary_kernel<<<N_GRAPHS, HID, 0, stream>>>(gsum, cnt, Ws, bs, out_sum);
}

// Round 10
// 223.693 us; speedup vs baseline: 1.9294x; 1.5907x over previous
//
#include <hip/hip_runtime.h>

#define N_NODES  100000
#define N_EDGES  1600000
#define IN_CH    128
#define HID      32
#define N_GRAPHS 64

#define NBIN   391            // bins of 256 dst nodes: bin = dst >> 8
#define CHUNK  4096           // edges per multisplit block; grid = 391
#define MGRID  391            // ceil(1.6M / 4096)
#define STG    5120           // csr2 per-bin staging capacity
#define LCAP   2048           // layer_kernel LDS index staging capacity (8 KB)

// workspace layout (4-byte element offsets) — total ~26.4 MB
#define OFF_B      0          // bf16[3,200,000] packed as uint[1,600,000]; H[391*391] aliases head
#define OFF_EDGEPK 3200000    // int[1,600,000]; gsum/cnt alias after csr2
#define OFF_CSR    4800000    // int[1,600,000]
#define OFF_COLT   6400000    // int[391]
#define OFF_BINB   6400391    // int[392]
#define OFF_ROWPTR 6400784    // int[100,001]
#define OFF_DINV   6500785    // float[100,000]

// bf16 pack (RNE) / unpack helpers
__device__ __forceinline__ unsigned bfr(float f) {
    unsigned u = __float_as_uint(f);
    u += 0x7fffu + ((u >> 16) & 1u);
    return u >> 16;
}
__device__ __forceinline__ float bflo(unsigned w) { return __uint_as_float(w << 16); }
__device__ __forceinline__ float bfhi(unsigned w) { return __uint_as_float(w & 0xffff0000u); }

// ---------- phase 1: per-(bin, wg) histogram ----------
__global__ __launch_bounds__(512) void hist_kernel(const int* __restrict__ dst,
                                                   int* __restrict__ H) {
    __shared__ int s[512];
    int t = threadIdx.x, wg = blockIdx.x;
    s[t] = 0;
    __syncthreads();
    int e0 = wg * CHUNK, e1 = min(e0 + CHUNK, N_EDGES);
    for (int e = e0 + t; e < e1; e += 512) {
        int d = dst[e];
        if ((unsigned)d < N_NODES) atomicAdd(&s[d >> 8], 1);
    }
    __syncthreads();
    if (t < NBIN) H[t * MGRID + wg] = s[t];
}

// ---------- phase 2a ----------
__global__ __launch_bounds__(512) void scanrow_kernel(int* __restrict__ H,
                                                      int* __restrict__ colT) {
    __shared__ int s[512];
    int t = threadIdx.x, bin = blockIdx.x;
    s[t] = (t < MGRID) ? H[bin * MGRID + t] : 0;
    __syncthreads();
    for (int off = 1; off < 512; off <<= 1) {
        int v = (t >= off) ? s[t - off] : 0;
        __syncthreads();
        if (t >= off) s[t] += v;
        __syncthreads();
    }
    if (t < MGRID) H[bin * MGRID + t] = t ? s[t - 1] : 0;
    if (t == 0) colT[bin] = s[MGRID - 1];
}

// ---------- phase 2b ----------
__global__ __launch_bounds__(512) void scanbase_kernel(const int* __restrict__ colT,
                                                       int* __restrict__ binB,
                                                       int* __restrict__ row_ptr) {
    __shared__ int s[512];
    int t = threadIdx.x;
    s[t] = (t < NBIN) ? colT[t] : 0;
    __syncthreads();
    for (int off = 1; off < 512; off <<= 1) {
        int v = (t >= off) ? s[t - off] : 0;
        __syncthreads();
        if (t >= off) s[t] += v;
        __syncthreads();
    }
    if (t < NBIN) binB[t] = t ? s[t - 1] : 0;
    if (t == 0) { binB[NBIN] = s[NBIN - 1]; row_ptr[N_NODES] = s[NBIN - 1]; }
}

// ---------- phase 3: bin-grouped scatter, LDS-staged coalesced flush ----------
__global__ __launch_bounds__(512) void msplit_kernel(const int* __restrict__ src,
                                                     const int* __restrict__ dst,
                                                     const int* __restrict__ H,
                                                     const int* __restrict__ binB,
                                                     int* __restrict__ edgepk) {
    __shared__ int s[512];
    __shared__ int cur[NBIN];
    __shared__ int gb[NBIN];
    __shared__ int stage[CHUNK];
    __shared__ int gof[CHUNK];
    int t = threadIdx.x, wg = blockIdx.x;
    s[t] = 0;
    __syncthreads();
    int e0 = wg * CHUNK, e1 = min(e0 + CHUNK, N_EDGES);
    for (int e = e0 + t; e < e1; e += 512) {
        int d = dst[e];
        if ((unsigned)d < N_NODES) atomicAdd(&s[d >> 8], 1);
    }
    __syncthreads();
    for (int off = 1; off < 512; off <<= 1) {
        int v = (t >= off) ? s[t - off] : 0;
        __syncthreads();
        if (t >= off) s[t] += v;
        __syncthreads();
    }
    if (t < NBIN) {
        int lo = t ? s[t - 1] : 0;
        cur[t] = lo;
        gb[t] = binB[t] + H[t * MGRID + wg] - lo;
    }
    __syncthreads();
    for (int e = e0 + t; e < e1; e += 512) {
        int d = dst[e];
        if ((unsigned)d < N_NODES) {
            int b = d >> 8;
            int p = atomicAdd(&cur[b], 1);
            stage[p] = (src[e] << 8) | (d & 255);
            gof[p] = gb[b];
        }
    }
    __syncthreads();
    int total = s[511];
    for (int p = t; p < total; p += 512)
        edgepk[gof[p] + p] = stage[p];
}

// ---------- phase 4: within-bin reorder -> CSR + dinv/row_ptr (512 thr) ----------
// 512-thread variant (validated as R8's fused phase 4): halves the serial
// strided rounds of both LDS-atomic passes vs the 256-thread original.
__global__ __launch_bounds__(512) void csr2_kernel(const int* __restrict__ edgepk,
                                                   const int* __restrict__ binB,
                                                   int* __restrict__ row_ptr,
                                                   float* __restrict__ dinv,
                                                   int* __restrict__ csr) {
    __shared__ int cnt[256], s[256], cur[256];
    __shared__ int stage[STG];
    int t = threadIdx.x, bin = blockIdx.x;
    int ebase = binB[bin], eend = binB[bin + 1];
    int n = eend - ebase;
    if (t < 256) cnt[t] = 0;
    __syncthreads();
    for (int p = ebase + t; p < eend; p += 512)
        atomicAdd(&cnt[edgepk[p] & 255], 1);
    __syncthreads();
    if (t < 256) s[t] = cnt[t];
    __syncthreads();
    for (int off = 1; off < 256; off <<= 1) {
        int v = (t >= off && t < 256) ? s[t - off] : 0;
        __syncthreads();
        if (t >= off && t < 256) s[t] += v;
        __syncthreads();
    }
    if (t < 256) {
        int excl = t ? s[t - 1] : 0;
        int node = (bin << 8) + t;
        if (node < N_NODES) {
            dinv[node] = rsqrtf((float)(cnt[t] + 1));
            row_ptr[node] = ebase + excl;
        }
        cur[t] = excl;
    }
    __syncthreads();
    for (int p = ebase + t; p < eend; p += 512) {
        int w = edgepk[p];
        int l = atomicAdd(&cur[w & 255], 1);
        int sv = w >> 8;
        if (l < STG) stage[l] = sv;
        else csr[ebase + l] = sv;
    }
    __syncthreads();
    int lim = min(n, STG);
    for (int l = t; l < lim; l += 512)
        csr[ebase + l] = stage[l];
}

// ---------- B(bf16) = (x @ W1) * dinv[row], register-tiled (4 ch/thread) ----------
// block 0 also zeroes gsum/cnt (aliased edgepk head, dead after csr2).
#define XS1 132               // 128 + 4 pad
__global__ __launch_bounds__(256) void gemm1_kernel(const float* __restrict__ x,
                                                    const float* __restrict__ W1,
                                                    const float* __restrict__ dinv,
                                                    unsigned* __restrict__ Bu,
                                                    float* __restrict__ gz) {
    __shared__ float Wl[IN_CH * HID];   // 16 KB
    __shared__ float xs[32 * XS1];      // 16.9 KB
    int tid = threadIdx.x;
    if (blockIdx.x == 0)
        for (int q = tid; q < N_GRAPHS * HID + N_GRAPHS; q += 256) gz[q] = 0.f;
    for (int j = tid; j < IN_CH * HID / 4; j += 256)
        ((float4*)Wl)[j] = ((const float4*)W1)[j];
    int row0 = blockIdx.x * 32;         // 100000 % 32 == 0
    const float4* x4 = (const float4*)(x + (size_t)row0 * IN_CH);
    for (int j = tid; j < 32 * IN_CH / 4; j += 256) {
        int r = j >> 5, k4 = j & 31;
        ((float4*)&xs[r * XS1])[k4] = x4[j];
    }
    __syncthreads();
    int r = tid >> 3, cg = (tid & 7) * 4;
    const float* xr = &xs[r * XS1];
    float4 acc = {0.f, 0.f, 0.f, 0.f};
    #pragma unroll 8
    for (int k = 0; k < IN_CH; ++k) {
        float xv = xr[k];
        float4 w = *(const float4*)&Wl[k * HID + cg];
        acc.x += xv * w.x; acc.y += xv * w.y; acc.z += xv * w.z; acc.w += xv * w.w;
    }
    int row = row0 + r;
    float dv = dinv[row];
    uint2 p;
    p.x = bfr(acc.x * dv) | (bfr(acc.y * dv) << 16);
    p.y = bfr(acc.z * dv) | (bfr(acc.w * dv) << 16);
    *(uint2*)&Bu[(size_t)row * 16 + (tid & 7) * 2] = p;
}

// ---------- B(bf16) = (in @ W2) * dinv[row], register-tiled ----------
#define XS2 36                // 32 + 4 pad
__global__ __launch_bounds__(256) void gemm2_kernel(const float* __restrict__ in,
                                                    const float* __restrict__ W2,
                                                    const float* __restrict__ dinv,
                                                    unsigned* __restrict__ Bu) {
    __shared__ float Wl[HID * HID];     // 4 KB
    __shared__ float xs[32 * XS2];      // 4.6 KB
    int tid = threadIdx.x;
    ((float4*)Wl)[tid] = ((const float4*)W2)[tid];
    int row0 = blockIdx.x * 32;
    const float4* in4 = (const float4*)(in + (size_t)row0 * HID);
    {
        int r = tid >> 3, k4 = tid & 7;
        ((float4*)&xs[r * XS2])[k4] = in4[tid];
    }
    __syncthreads();
    int r = tid >> 3, cg = (tid & 7) * 4;
    const float* xr = &xs[r * XS2];
    float4 acc = {0.f, 0.f, 0.f, 0.f};
    #pragma unroll
    for (int k = 0; k < HID; ++k) {
        float xv = xr[k];
        float4 w = *(const float4*)&Wl[k * HID + cg];
        acc.x += xv * w.x; acc.y += xv * w.y; acc.z += xv * w.z; acc.w += xv * w.w;
    }
    int row = row0 + r;
    float dv = dinv[row];
    uint2 p;
    p.x = bfr(acc.x * dv) | (bfr(acc.y * dv) << 16);
    p.y = bfr(acc.z * dv) | (bfr(acc.w * dv) << 16);
    *(uint2*)&Bu[(size_t)row * 16 + (tid & 7) * 2] = p;
}

// ---------- gather layer: LDS-staged indices + uint4 Bu gathers (R6-proven) ----------
__global__ __launch_bounds__(256) void layer_kernel(const unsigned* __restrict__ Bu,
                                                    const int* __restrict__ csr,
                                                    const int* __restrict__ row_ptr,
                                                    const float* __restrict__ dinv,
                                                    const float* __restrict__ bias,
                                                    float* __restrict__ out,
                                                    int relu) {
    __shared__ int sidx[LCAP];          // 8 KB
    int tid = threadIdx.x;
    int n0 = blockIdx.x * 64;           // grid 1563, tail guarded
    int nend = min(n0 + 64, N_NODES);
    int j0 = row_ptr[n0], j1 = row_ptr[nend];
    int nblk = j1 - j0;
    int staged = (nblk <= LCAP);
    if (staged)
        for (int p = tid; p < nblk; p += 256) sidx[p] = csr[j0 + p];
    __syncthreads();
    int node = n0 + (tid >> 2);
    if (node >= N_NODES) return;
    int c4 = tid & 3;                   // owns channels 8*c4 .. 8*c4+7
    const uint4* Br = (const uint4*)Bu; // 4 uint4 per node row
    uint4 sw = Br[(size_t)node * 4 + c4];   // self-loop term
    float a0 = bflo(sw.x), a1 = bfhi(sw.x);
    float a2 = bflo(sw.y), a3 = bfhi(sw.y);
    float a4 = bflo(sw.z), a5 = bfhi(sw.z);
    float a6 = bflo(sw.w), a7 = bfhi(sw.w);
    if (staged) {
        int j = row_ptr[node] - j0, re = row_ptr[node + 1] - j0;
        for (; j + 8 <= re; j += 8) {
            int s0 = sidx[j + 0], s1 = sidx[j + 1], s2 = sidx[j + 2], s3 = sidx[j + 3];
            int s4 = sidx[j + 4], s5 = sidx[j + 5], s6 = sidx[j + 6], s7 = sidx[j + 7];
            uint4 w0 = Br[(size_t)s0 * 4 + c4], w1 = Br[(size_t)s1 * 4 + c4];
            uint4 w2 = Br[(size_t)s2 * 4 + c4], w3 = Br[(size_t)s3 * 4 + c4];
            uint4 w4 = Br[(size_t)s4 * 4 + c4], w5 = Br[(size_t)s5 * 4 + c4];
            uint4 w6 = Br[(size_t)s6 * 4 + c4], w7 = Br[(size_t)s7 * 4 + c4];
            a0 += ((bflo(w0.x) + bflo(w1.x)) + (bflo(w2.x) + bflo(w3.x)))
                + ((bflo(w4.x) + bflo(w5.x)) + (bflo(w6.x) + bflo(w7.x)));
            a1 += ((bfhi(w0.x) + bfhi(w1.x)) + (bfhi(w2.x) + bfhi(w3.x)))
                + ((bfhi(w4.x) + bfhi(w5.x)) + (bfhi(w6.x) + bfhi(w7.x)));
            a2 += ((bflo(w0.y) + bflo(w1.y)) + (bflo(w2.y) + bflo(w3.y)))
                + ((bflo(w4.y) + bflo(w5.y)) + (bflo(w6.y) + bflo(w7.y)));
            a3 += ((bfhi(w0.y) + bfhi(w1.y)) + (bfhi(w2.y) + bfhi(w3.y)))
                + ((bfhi(w4.y) + bfhi(w5.y)) + (bfhi(w6.y) + bfhi(w7.y)));
            a4 += ((bflo(w0.z) + bflo(w1.z)) + (bflo(w2.z) + bflo(w3.z)))
                + ((bflo(w4.z) + bflo(w5.z)) + (bflo(w6.z) + bflo(w7.z)));
            a5 += ((bfhi(w0.z) + bfhi(w1.z)) + (bfhi(w2.z) + bfhi(w3.z)))
                + ((bfhi(w4.z) + bfhi(w5.z)) + (bfhi(w6.z) + bfhi(w7.z)));
            a6 += ((bflo(w0.w) + bflo(w1.w)) + (bflo(w2.w) + bflo(w3.w)))
                + ((bflo(w4.w) + bflo(w5.w)) + (bflo(w6.w) + bflo(w7.w)));
            a7 += ((bfhi(w0.w) + bfhi(w1.w)) + (bfhi(w2.w) + bfhi(w3.w)))
                + ((bfhi(w4.w) + bfhi(w5.w)) + (bfhi(w6.w) + bfhi(w7.w)));
        }
        if (j + 4 <= re) {
            int s0 = sidx[j], s1 = sidx[j + 1], s2 = sidx[j + 2], s3 = sidx[j + 3];
            uint4 w0 = Br[(size_t)s0 * 4 + c4], w1 = Br[(size_t)s1 * 4 + c4];
            uint4 w2 = Br[(size_t)s2 * 4 + c4], w3 = Br[(size_t)s3 * 4 + c4];
            a0 += (bflo(w0.x) + bflo(w1.x)) + (bflo(w2.x) + bflo(w3.x));
            a1 += (bfhi(w0.x) + bfhi(w1.x)) + (bfhi(w2.x) + bfhi(w3.x));
            a2 += (bflo(w0.y) + bflo(w1.y)) + (bflo(w2.y) + bflo(w3.y));
            a3 += (bfhi(w0.y) + bfhi(w1.y)) + (bfhi(w2.y) + bfhi(w3.y));
            a4 += (bflo(w0.z) + bflo(w1.z)) + (bflo(w2.z) + bflo(w3.z));
            a5 += (bfhi(w0.z) + bfhi(w1.z)) + (bfhi(w2.z) + bfhi(w3.z));
            a6 += (bflo(w0.w) + bflo(w1.w)) + (bflo(w2.w) + bflo(w3.w));
            a7 += (bfhi(w0.w) + bfhi(w1.w)) + (bfhi(w2.w) + bfhi(w3.w));
            j += 4;
        }
        for (; j < re; ++j) {
            uint4 w = Br[(size_t)sidx[j] * 4 + c4];
            a0 += bflo(w.x); a1 += bfhi(w.x);
            a2 += bflo(w.y); a3 += bfhi(w.y);
            a4 += bflo(w.z); a5 += bfhi(w.z);
            a6 += bflo(w.w); a7 += bfhi(w.w);
        }
    } else {
        int j = row_ptr[node], re = row_ptr[node + 1];
        for (; j < re; ++j) {
            uint4 w = Br[(size_t)csr[j] * 4 + c4];
            a0 += bflo(w.x); a1 += bfhi(w.x);
            a2 += bflo(w.y); a3 += bfhi(w.y);
            a4 += bflo(w.z); a5 += bfhi(w.z);
            a6 += bflo(w.w); a7 += bfhi(w.w);
        }
    }
    float dv = dinv[node];
    float4 bA = *(const float4*)&bias[8 * c4];
    float4 bB = *(const float4*)&bias[8 * c4 + 4];
    float4 o1, o2;
    o1.x = a0 * dv + bA.x; o1.y = a1 * dv + bA.y;
    o1.z = a2 * dv + bA.z; o1.w = a3 * dv + bA.w;
    o2.x = a4 * dv + bB.x; o2.y = a5 * dv + bB.y;
    o2.z = a6 * dv + bB.z; o2.w = a7 * dv + bB.w;
    if (relu) {
        o1.x = fmaxf(o1.x, 0.f); o1.y = fmaxf(o1.y, 0.f);
        o1.z = fmaxf(o1.z, 0.f); o1.w = fmaxf(o1.w, 0.f);
        o2.x = fmaxf(o2.x, 0.f); o2.y = fmaxf(o2.y, 0.f);
        o2.z = fmaxf(o2.z, 0.f); o2.w = fmaxf(o2.w, 0.f);
    }
    float* orow = out + (size_t)node * HID + 8 * c4;
    *(float4*)orow = o1;
    *(float4*)(orow + 4) = o2;
}

// ---------- per-graph mean-pool: register run-accumulation + span flush ----------
__global__ __launch_bounds__(256) void pool_kernel(const float* __restrict__ h,
                                                   const int* __restrict__ batch,
                                                   float* __restrict__ gsum,
                                                   float* __restrict__ cnt) {
    __shared__ float pool[N_GRAPHS * HID];  // 8 KB
    __shared__ float cntl[N_GRAPHS];
    __shared__ int gmin, gmax;
    int t = threadIdx.x;
    for (int j = t; j < N_GRAPHS * HID; j += 256) pool[j] = 0.f;
    if (t < N_GRAPHS) cntl[t] = 0.f;
    if (t == 0) { gmin = N_GRAPHS; gmax = -1; }
    __syncthreads();
    int start = blockIdx.x * 256;
    int end = min(start + 256, N_NODES);
    int c = t & 31;
    float racc = 0.f;
    int rg = -1, rcnt = 0;
    for (int nb = start + (t >> 5); nb < end; nb += 8) {
        float v = h[(size_t)nb * HID + c];
        int g = batch[nb];
        if (g != rg) {
            if ((unsigned)rg < N_GRAPHS) {
                atomicAdd(&pool[rg * HID + c], racc);
                if (c == 0) {
                    atomicAdd(&cntl[rg], (float)rcnt);
                    atomicMin(&gmin, rg); atomicMax(&gmax, rg);
                }
            }
            rg = g; racc = v; rcnt = 1;
        } else { racc += v; ++rcnt; }
    }
    if ((unsigned)rg < N_GRAPHS) {
        atomicAdd(&pool[rg * HID + c], racc);
        if (c == 0) {
            atomicAdd(&cntl[rg], (float)rcnt);
            atomicMin(&gmin, rg); atomicMax(&gmax, rg);
        }
    }
    __syncthreads();
    int lo = gmin, hi = gmax;
    if (hi >= lo) {
        int span = (hi - lo + 1) * HID;
        for (int j = t; j < span; j += 256)
            atomicAdd(&gsum[lo * HID + j], pool[lo * HID + j]);
        for (int j = t; j <= hi - lo; j += 256)
            atomicAdd(&cnt[lo + j], cntl[lo + j]);
    }
}

__global__ void summary_kernel(const float* __restrict__ gsum, const float* __restrict__ cnt,
                               const float* __restrict__ Ws, const float* __restrict__ bs,
                               float* __restrict__ out) {
    int g = blockIdx.x, c = threadIdx.x;
    float inv = 1.f / fmaxf(cnt[g], 1.f);
    float acc = bs[c];
    #pragma unroll
    for (int k = 0; k < HID; ++k)
        acc += gsum[g * HID + k] * inv * Ws[k * HID + c];
    out[g * HID + c] = acc;
}

extern "C" void kernel_launch(void* const* d_in, const int* in_sizes, int n_in,
                              void* d_out, int out_size, void* d_ws, size_t ws_size,
                              hipStream_t stream) {
    const float* x    = (const float*)d_in[0];
    const int* edge   = (const int*)d_in[1];
    const int* src    = edge;
    const int* dst    = edge + N_EDGES;
    const int* batch  = (const int*)d_in[2];
    const float* W1   = (const float*)d_in[3];
    const float* b1   = (const float*)d_in[4];
    const float* W2   = (const float*)d_in[5];
    const float* b2   = (const float*)d_in[6];
    const float* Ws   = (const float*)d_in[7];
    const float* bs   = (const float*)d_in[8];

    float* ws      = (float*)d_ws;
    unsigned* Bu   = (unsigned*)(ws + OFF_B);   // bf16-packed B
    int*   H       = (int*)(ws + OFF_B);        // aliases B head; dead before gemm1
    int*   edgepk  = (int*)(ws + OFF_EDGEPK);
    int*   csr     = (int*)(ws + OFF_CSR);
    int*   colT    = (int*)(ws + OFF_COLT);
    int*   binB    = (int*)(ws + OFF_BINB);
    int*   row_ptr = (int*)(ws + OFF_ROWPTR);
    float* dinv    = ws + OFF_DINV;
    float* gsum    = ws + OFF_EDGEPK;           // aliases edgepk (dead after csr2)
    float* cnt     = gsum + N_GRAPHS * HID;

    float* out     = (float*)d_out;
    float* out_sum = out;
    float* out_h   = out + N_GRAPHS * HID;

    // CSR build
    hist_kernel    <<<MGRID, 512, 0, stream>>>(dst, H);
    scanrow_kernel <<<NBIN,  512, 0, stream>>>(H, colT);
    scanbase_kernel<<<1,     512, 0, stream>>>(colT, binB, row_ptr);
    msplit_kernel  <<<MGRID, 512, 0, stream>>>(src, dst, H, binB, edgepk);
    csr2_kernel    <<<NBIN,  512, 0, stream>>>(edgepk, binB, row_ptr, dinv, csr);

    int lgrid = (N_NODES + 63) / 64;   // 1563

    // layer 1 (gemm1 block 0 zeroes gsum/cnt)
    gemm1_kernel<<<N_NODES / 32, 256, 0, stream>>>(x, W1, dinv, Bu, gsum);
    layer_kernel<<<lgrid, 256, 0, stream>>>(Bu, csr, row_ptr, dinv, b1, out_h, 1);

    // layer 2
    gemm2_kernel<<<N_NODES / 32, 256, 0, stream>>>(out_h, W2, dinv, Bu);
    layer_kernel<<<lgrid, 256, 0, stream>>>(Bu, csr, row_ptr, dinv, b2, out_h, 0);

    // pooling + summary
    pool_kernel<<<NBIN, 256, 0, stream>>>(out_h, batch, gsum, cnt);
    summary_kernel<<<N_GRAPHS, HID, 0, stream>>>(gsum, cnt, Ws, bs, out_sum);
}